// Round 1
// baseline (227.583 us; speedup 1.0000x reference)
//
#include <hip/hip_runtime.h>

constexpr int RES  = 256;   // image resolution, rays per angle, steps per ray
constexpr int NANG = 180;
constexpr int NB   = 4;

__global__ __launch_bounds__(256)
void radon_fwd(const float* __restrict__ imgs,
               const float* __restrict__ angles,
               const float* __restrict__ rays,
               float* __restrict__ out)
{
    const int r = threadIdx.x;          // ray index 0..255
    const int a = blockIdx.x % NANG;    // angle index
    const int b = blockIdx.x / NANG;    // batch index

    // rays[r] = (sx, sy, ex, ey) = (loc, -ys, loc, ys)
    const float4 ray = reinterpret_cast<const float4*>(rays)[r];
    const float ang = angles[a];
    float sn, cs;
    sincosf(ang, &sn, &cs);

    // rotate endpoints
    const float rsx = ray.x * cs - ray.y * sn;
    const float rsy = ray.x * sn + ray.y * cs;
    const float rex = ray.z * cs - ray.w * sn;
    const float rey = ray.z * sn + ray.w * cs;

    const float ddx = rex - rsx;
    const float ddy = rey - rsy;
    const float bx  = rsx + 127.5f;     // + (s - 0.5)
    const float by  = rsy + 127.5f;

    const float* __restrict__ img = imgs + b * (RES * RES);

    float acc = 0.0f;
#pragma unroll 4
    for (int i = 0; i < RES; ++i) {
        const float t  = ((float)i + 0.5f) * (1.0f / (float)RES);
        const float fx = fmaf(ddx, t, bx);
        const float fy = fmaf(ddy, t, by);

        const float x0f = floorf(fx);
        const float y0f = floorf(fy);
        const int   x0  = (int)x0f;
        const int   y0  = (int)y0f;
        const float wx  = fx - x0f;
        const float wy  = fy - y0f;

        // clamped addresses (always-valid loads), validity as selects
        const int xc0 = min(max(x0, 0), RES - 1);
        const int xc1 = min(max(x0 + 1, 0), RES - 1);
        const int yc0 = min(max(y0, 0), RES - 1);
        const int yc1 = min(max(y0 + 1, 0), RES - 1);

        const bool vx0 = (unsigned)x0       < (unsigned)RES;
        const bool vx1 = (unsigned)(x0 + 1) < (unsigned)RES;
        const bool vy0 = (unsigned)y0       < (unsigned)RES;
        const bool vy1 = (unsigned)(y0 + 1) < (unsigned)RES;

        const float* row0 = img + yc0 * RES;
        const float* row1 = img + yc1 * RES;
        float v00 = row0[xc0]; if (!(vx0 && vy0)) v00 = 0.0f;
        float v01 = row0[xc1]; if (!(vx1 && vy0)) v01 = 0.0f;
        float v10 = row1[xc0]; if (!(vx0 && vy1)) v10 = 0.0f;
        float v11 = row1[xc1]; if (!(vx1 && vy1)) v11 = 0.0f;

        const float top = (1.0f - wx) * v00 + wx * v01;
        const float bot = (1.0f - wx) * v10 + wx * v11;
        acc += (1.0f - wy) * top + wy * bot;
    }

    // step = L / n_steps = (ey - sy) / RES
    const float step = (ray.w - ray.y) * (1.0f / (float)RES);
    out[(b * NANG + a) * RES + r] = acc * step;
}

extern "C" void kernel_launch(void* const* d_in, const int* in_sizes, int n_in,
                              void* d_out, int out_size, void* d_ws, size_t ws_size,
                              hipStream_t stream)
{
    const float* imgs   = (const float*)d_in[0];
    const float* angles = (const float*)d_in[1];
    const float* rays   = (const float*)d_in[2];
    float* out = (float*)d_out;

    dim3 grid(NB * NANG);
    dim3 block(RES);
    radon_fwd<<<grid, block, 0, stream>>>(imgs, angles, rays, out);
}

// Round 2
// 158.160 us; speedup vs baseline: 1.4389x; 1.4389x over previous
//
#include <hip/hip_runtime.h>

constexpr int RES  = 256;   // image resolution, rays per angle, steps per ray
constexpr int NANG = 180;
constexpr int NB   = 4;

// Wave tiling: lane = cq*8 + rq
//   rq (lane&7)  -> 8 consecutive rays
//   cq (lane>>3) -> 8 consecutive steps processed concurrently (thread steps are
//                   strided by 8), so a wave's 64 gathers form a compact rotated
//                   ~8x8-pixel tile for ANY angle -> few cache-line splits.
// Each thread accumulates 32 samples; 3 shfl_down reduce over cq; lanes 0..7
// (cq==0) write the 8 rays owned by the wave.
__global__ __launch_bounds__(256)
void radon_fwd(const float* __restrict__ imgs,
               const float* __restrict__ angles,
               const float* __restrict__ rays,
               float* __restrict__ out)
{
    const int tid  = threadIdx.x;
    const int wave = tid >> 6;
    const int lane = tid & 63;
    const int cq   = lane >> 3;   // step phase 0..7
    const int rq   = lane & 7;    // ray within the wave's 8-ray group

    const int pair = blockIdx.x >> 3;     // (b, a) pair
    const int rblk = blockIdx.x & 7;      // 32-ray block within the 256 rays
    const int a = pair % NANG;
    const int b = pair / NANG;
    const int r = rblk * 32 + wave * 8 + rq;

    // rays[r] = (sx, sy, ex, ey) = (loc, -ys, loc, ys)
    const float4 ray = reinterpret_cast<const float4*>(rays)[r];
    float sn, cs;
    sincosf(angles[a], &sn, &cs);

    const float rsx = ray.x * cs - ray.y * sn;
    const float rsy = ray.x * sn + ray.y * cs;
    const float rex = ray.z * cs - ray.w * sn;
    const float rey = ray.z * sn + ray.w * cs;

    const float ddx = rex - rsx;
    const float ddy = rey - rsy;
    const float bx  = rsx + 127.5f;     // + (s - 0.5)
    const float by  = rsy + 127.5f;

    const float* __restrict__ img = imgs + b * (RES * RES);

    float acc = 0.0f;
#pragma unroll 4
    for (int j = 0; j < 32; ++j) {
        const int   i  = j * 8 + cq;                       // this thread's step
        const float t  = ((float)i + 0.5f) * (1.0f / 256.0f);
        const float fx = fmaf(ddx, t, bx);
        const float fy = fmaf(ddy, t, by);

        const float x0f = floorf(fx);
        const float y0f = floorf(fy);
        const int   x0  = (int)x0f;
        const int   y0  = (int)y0f;
        const float wx  = fx - x0f;
        const float wy  = fy - y0f;

        const int xc0 = min(max(x0, 0), RES - 1);
        const int xc1 = min(max(x0 + 1, 0), RES - 1);
        const int yc0 = min(max(y0, 0), RES - 1);
        const int yc1 = min(max(y0 + 1, 0), RES - 1);

        const bool vx0 = (unsigned)x0       < (unsigned)RES;
        const bool vx1 = (unsigned)(x0 + 1) < (unsigned)RES;
        const bool vy0 = (unsigned)y0       < (unsigned)RES;
        const bool vy1 = (unsigned)(y0 + 1) < (unsigned)RES;

        const int row0 = yc0 * RES;
        const int row1 = yc1 * RES;
        float v00 = img[row0 + xc0]; if (!(vx0 && vy0)) v00 = 0.0f;
        float v01 = img[row0 + xc1]; if (!(vx1 && vy0)) v01 = 0.0f;
        float v10 = img[row1 + xc0]; if (!(vx0 && vy1)) v10 = 0.0f;
        float v11 = img[row1 + xc1]; if (!(vx1 && vy1)) v11 = 0.0f;

        const float top = (1.0f - wx) * v00 + wx * v01;
        const float bot = (1.0f - wx) * v10 + wx * v11;
        acc += (1.0f - wy) * top + wy * bot;
    }

    // per-ray step length: (ey - sy) / n_steps  (same for all cq of this ray)
    acc *= (ray.w - ray.y) * (1.0f / 256.0f);

    // reduce over the 8 step-phases (cq axis, stride 8 in lane space)
    acc += __shfl_down(acc, 32);
    acc += __shfl_down(acc, 16);
    acc += __shfl_down(acc, 8);

    if (cq == 0)
        out[(b * NANG + a) * RES + r] = acc;
}

extern "C" void kernel_launch(void* const* d_in, const int* in_sizes, int n_in,
                              void* d_out, int out_size, void* d_ws, size_t ws_size,
                              hipStream_t stream)
{
    const float* imgs   = (const float*)d_in[0];
    const float* angles = (const float*)d_in[1];
    const float* rays   = (const float*)d_in[2];
    float* out = (float*)d_out;

    dim3 grid(NB * NANG * 8);   // 8 ray-blocks per (batch, angle)
    dim3 block(256);
    radon_fwd<<<grid, block, 0, stream>>>(imgs, angles, rays, out);
}

// Round 3
// 128.384 us; speedup vs baseline: 1.7727x; 1.2319x over previous
//
#include <hip/hip_runtime.h>

constexpr int RES  = 256;   // image resolution, rays per angle, steps per ray
constexpr int NANG = 180;
constexpr int NB   = 4;

typedef float f2_t __attribute__((ext_vector_type(2), aligned(4)));

// Wave tiling: lane = cq*8 + rq
//   rq (lane&7)  -> 8 consecutive rays
//   cq (lane>>3) -> 8 step-phases (thread's steps strided by 8), so a wave's
//   64 gathers form a compact rotated ~8x8-pixel tile at ANY angle.
// Per bilinear sample: 2x 8-byte gathers (x-pair per row) instead of 4 dwords.
__global__ __launch_bounds__(256)
void radon_fwd(const float* __restrict__ imgs,
               const float* __restrict__ angles,
               const float* __restrict__ rays,
               float* __restrict__ out)
{
    const int tid  = threadIdx.x;
    const int wave = tid >> 6;
    const int lane = tid & 63;
    const int cq   = lane >> 3;   // step phase 0..7
    const int rq   = lane & 7;    // ray within the wave's 8-ray group

    const int pair = blockIdx.x >> 3;     // (b, a) pair
    const int rblk = blockIdx.x & 7;      // 32-ray block within the 256 rays
    const int a = pair % NANG;
    const int b = pair / NANG;
    const int r = rblk * 32 + wave * 8 + rq;

    // rays[r] = (sx, sy, ex, ey) = (loc, -ys, loc, ys)
    const float4 ray = reinterpret_cast<const float4*>(rays)[r];
    float sn, cs;
    sincosf(angles[a], &sn, &cs);

    const float rsx = ray.x * cs - ray.y * sn;
    const float rsy = ray.x * sn + ray.y * cs;
    const float rex = ray.z * cs - ray.w * sn;
    const float rey = ray.z * sn + ray.w * cs;

    const float ddx = rex - rsx;
    const float ddy = rey - rsy;
    const float bx  = rsx + 127.5f;     // + (s - 0.5)
    const float by  = rsy + 127.5f;

    const float* __restrict__ img = imgs + b * (RES * RES);

    float acc = 0.0f;
#pragma unroll 4
    for (int j = 0; j < 32; ++j) {
        const int   i  = j * 8 + cq;                       // this thread's step
        const float t  = ((float)i + 0.5f) * (1.0f / 256.0f);
        const float fx = fmaf(ddx, t, bx);
        const float fy = fmaf(ddy, t, by);

        const float x0f = floorf(fx);
        const float y0f = floorf(fy);
        const int   x0  = (int)x0f;
        const int   y0  = (int)y0f;
        const float wx  = fx - x0f;
        const float wy  = fy - y0f;

        // pair base clamped so the 8B load [xs, xs+1] is always in-row
        const int xs  = min(max(x0, 0), RES - 2);          // v_med3_i32
        const int yc0 = min(max(y0, 0), RES - 1);
        const int yc1 = min(max(y0 + 1, 0), RES - 1);

        const f2_t p0 = *reinterpret_cast<const f2_t*>(img + yc0 * RES + xs);
        const f2_t p1 = *reinterpret_cast<const f2_t*>(img + yc1 * RES + xs);

        // reorder pair for edge cases (x0==-1 -> v01=p.x ; x0==255 -> v00=p.y)
        const bool straight = (x0 == xs);
        const float v00 = straight ? p0.x : p0.y;
        const float v01 = straight ? p0.y : p0.x;
        const float v10 = straight ? p1.x : p1.y;
        const float v11 = straight ? p1.y : p1.x;

        // fold validity into the weights (clamped loads are always in-bounds)
        const bool vx0 = (unsigned)x0       < (unsigned)RES;
        const bool vx1 = (unsigned)(x0 + 1) < (unsigned)RES;
        const bool vy0 = (unsigned)y0       < (unsigned)RES;
        const bool vy1 = (unsigned)(y0 + 1) < (unsigned)RES;
        const float wxa = vx0 ? (1.0f - wx) : 0.0f;
        const float wxb = vx1 ? wx          : 0.0f;
        const float wya = vy0 ? (1.0f - wy) : 0.0f;
        const float wyb = vy1 ? wy          : 0.0f;

        const float top = wxa * v00 + wxb * v01;
        const float bot = wxa * v10 + wxb * v11;
        acc += wya * top + wyb * bot;
    }

    // per-ray scale: step = (ey - sy) / n_steps
    acc *= (ray.w - ray.y) * (1.0f / 256.0f);

    // reduce over the 8 step-phases (cq axis, stride 8 in lane space)
    acc += __shfl_down(acc, 32);
    acc += __shfl_down(acc, 16);
    acc += __shfl_down(acc, 8);

    if (cq == 0)
        out[(b * NANG + a) * RES + r] = acc;
}

extern "C" void kernel_launch(void* const* d_in, const int* in_sizes, int n_in,
                              void* d_out, int out_size, void* d_ws, size_t ws_size,
                              hipStream_t stream)
{
    const float* imgs   = (const float*)d_in[0];
    const float* angles = (const float*)d_in[1];
    const float* rays   = (const float*)d_in[2];
    float* out = (float*)d_out;

    dim3 grid(NB * NANG * 8);   // 8 ray-blocks per (batch, angle)
    dim3 block(256);
    radon_fwd<<<grid, block, 0, stream>>>(imgs, angles, rays, out);
}

// Round 4
// 51.790 us; speedup vs baseline: 4.3943x; 2.4789x over previous
//
#include <hip/hip_runtime.h>

constexpr int RES  = 256;   // image resolution, rays per angle, steps per ray
constexpr int NANG = 180;
constexpr int NB   = 4;
constexpr int SX   = 260;   // packed row stride in float2 elements (1 pad col used)
constexpr size_t PACK_BYTES = (size_t)NB * RES * SX * 8;

typedef float f2_t __attribute__((ext_vector_type(2), aligned(4)));
typedef float f4_t __attribute__((ext_vector_type(4), aligned(8)));

// ---------------------------------------------------------------------------
// Pack: P[b][y][x] = (img[y][x], img[min(y+1,255)][x]), x in [0,255], plus a
// pad element at x=256 duplicating x=255. One 16B load at (y,x) then yields
// all 4 bilinear taps: (v00, v10, v01, v11).
// ---------------------------------------------------------------------------
__global__ __launch_bounds__(256)
void pack_dualrow(const float* __restrict__ imgs, f2_t* __restrict__ P)
{
    const int x = threadIdx.x;
    const int y = blockIdx.x & (RES - 1);
    const int b = blockIdx.x >> 8;
    const float* __restrict__ img = imgs + b * (RES * RES);
    const int yp = min(y + 1, RES - 1);
    f2_t v;
    v.x = img[y * RES + x];
    v.y = img[yp * RES + x];
    f2_t* row = P + (size_t)(b * RES + y) * SX;
    row[x] = v;
    if (x == RES - 1) row[RES] = v;   // pad col (only ever read with weight 0)
}

// ---------------------------------------------------------------------------
// Main: lane = cq*8 + rq  (8 rays x 8 step-phases per wave -> compact rotated
// ~8x8 px tile per wave-gather at any angle). 1 dwordx4 gather per sample.
// Inner loop batched 4-wide: 4 addresses+loads issued, then 4 consumed.
// ---------------------------------------------------------------------------
__global__ __launch_bounds__(256)
void radon_fwd_packed(const f2_t* __restrict__ P,
                      const float* __restrict__ angles,
                      const float* __restrict__ rays,
                      float* __restrict__ out)
{
    const int tid  = threadIdx.x;
    const int wave = tid >> 6;
    const int lane = tid & 63;
    const int cq   = lane >> 3;   // step phase 0..7
    const int rq   = lane & 7;    // ray within the wave's 8-ray group

    const int pair = blockIdx.x >> 3;
    const int rblk = blockIdx.x & 7;
    const int a = pair % NANG;
    const int b = pair / NANG;
    const int r = rblk * 32 + wave * 8 + rq;

    const float4 ray = reinterpret_cast<const float4*>(rays)[r];
    float sn, cs;
    sincosf(angles[a], &sn, &cs);

    const float rsx = ray.x * cs - ray.y * sn;
    const float rsy = ray.x * sn + ray.y * cs;
    const float rex = ray.z * cs - ray.w * sn;
    const float rey = ray.z * sn + ray.w * cs;

    const float ddx = rex - rsx;
    const float ddy = rey - rsy;
    const float bx  = rsx + 127.5f;
    const float by  = rsy + 127.5f;

    const f2_t* __restrict__ Pb = P + (size_t)b * RES * SX;

    float acc = 0.0f;
#pragma unroll
    for (int jo = 0; jo < 32; jo += 4) {
        f4_t  p[4];
        float wxa[4], wxb[4], wya[4], wyb[4];
        bool  sx[4], sy[4];

        // --- phase 1: addresses + weights, issue 4 independent loads ---
#pragma unroll
        for (int u = 0; u < 4; ++u) {
            const int   i  = (jo + u) * 8 + cq;
            const float t  = ((float)i + 0.5f) * (1.0f / 256.0f);
            const float fx = fmaf(ddx, t, bx);
            const float fy = fmaf(ddy, t, by);

            const float x0f = floorf(fx);
            const float y0f = floorf(fy);
            const int   x0  = (int)x0f;
            const int   y0  = (int)y0f;
            const float wx  = fx - x0f;
            const float wy  = fy - y0f;

            const int xs = max(x0, 0);
            const int ys = max(y0, 0);
            sx[u] = (x0 >= 0);
            sy[u] = (y0 >= 0);
            wxa[u] = sx[u]        ? (1.0f - wx) : 0.0f;
            wxb[u] = (x0 <= 254)  ? wx          : 0.0f;
            wya[u] = sy[u]        ? (1.0f - wy) : 0.0f;
            wyb[u] = (y0 <= 254)  ? wy          : 0.0f;

            const int off = ys * SX + xs;            // element offset
            p[u] = *reinterpret_cast<const f4_t*>(Pb + off);
        }

        // --- phase 2: consume ---
#pragma unroll
        for (int u = 0; u < 4; ++u) {
            const f4_t f4 = p[u];
            // f4 = (img[ys][xs], img[ysp][xs], img[ys][xs+1], img[ysp][xs+1])
            const float v00 = f4.x;
            const float v01 = sx[u] ? f4.z : f4.x;
            const float v10 = sy[u] ? f4.y : f4.x;
            const float v11 = sy[u] ? (sx[u] ? f4.w : f4.y)
                                    : (sx[u] ? f4.z : f4.x);
            const float top = wxa[u] * v00 + wxb[u] * v01;
            const float bot = wxa[u] * v10 + wxb[u] * v11;
            acc += wya[u] * top + wyb[u] * bot;
        }
    }

    acc *= (ray.w - ray.y) * (1.0f / 256.0f);   // * step

    acc += __shfl_down(acc, 32);
    acc += __shfl_down(acc, 16);
    acc += __shfl_down(acc, 8);

    if (cq == 0)
        out[(b * NANG + a) * RES + r] = acc;
}

// ---------------------------------------------------------------------------
// Fallback (R3 kernel): used only if ws_size can't hold the packed image.
// ---------------------------------------------------------------------------
__global__ __launch_bounds__(256)
void radon_fwd_fallback(const float* __restrict__ imgs,
                        const float* __restrict__ angles,
                        const float* __restrict__ rays,
                        float* __restrict__ out)
{
    const int tid  = threadIdx.x;
    const int wave = tid >> 6;
    const int lane = tid & 63;
    const int cq   = lane >> 3;
    const int rq   = lane & 7;

    const int pair = blockIdx.x >> 3;
    const int rblk = blockIdx.x & 7;
    const int a = pair % NANG;
    const int b = pair / NANG;
    const int r = rblk * 32 + wave * 8 + rq;

    const float4 ray = reinterpret_cast<const float4*>(rays)[r];
    float sn, cs;
    sincosf(angles[a], &sn, &cs);

    const float rsx = ray.x * cs - ray.y * sn;
    const float rsy = ray.x * sn + ray.y * cs;
    const float rex = ray.z * cs - ray.w * sn;
    const float rey = ray.z * sn + ray.w * cs;

    const float ddx = rex - rsx;
    const float ddy = rey - rsy;
    const float bx  = rsx + 127.5f;
    const float by  = rsy + 127.5f;

    const float* __restrict__ img = imgs + b * (RES * RES);

    float acc = 0.0f;
#pragma unroll 4
    for (int j = 0; j < 32; ++j) {
        const int   i  = j * 8 + cq;
        const float t  = ((float)i + 0.5f) * (1.0f / 256.0f);
        const float fx = fmaf(ddx, t, bx);
        const float fy = fmaf(ddy, t, by);

        const float x0f = floorf(fx);
        const float y0f = floorf(fy);
        const int   x0  = (int)x0f;
        const int   y0  = (int)y0f;
        const float wx  = fx - x0f;
        const float wy  = fy - y0f;

        const int xs  = min(max(x0, 0), RES - 2);
        const int yc0 = min(max(y0, 0), RES - 1);
        const int yc1 = min(max(y0 + 1, 0), RES - 1);

        const f2_t p0 = *reinterpret_cast<const f2_t*>(img + yc0 * RES + xs);
        const f2_t p1 = *reinterpret_cast<const f2_t*>(img + yc1 * RES + xs);

        const bool straight = (x0 == xs);
        const float v00 = straight ? p0.x : p0.y;
        const float v01 = straight ? p0.y : p0.x;
        const float v10 = straight ? p1.x : p1.y;
        const float v11 = straight ? p1.y : p1.x;

        const bool vx0 = (unsigned)x0       < (unsigned)RES;
        const bool vx1 = (unsigned)(x0 + 1) < (unsigned)RES;
        const bool vy0 = (unsigned)y0       < (unsigned)RES;
        const bool vy1 = (unsigned)(y0 + 1) < (unsigned)RES;
        const float wxa = vx0 ? (1.0f - wx) : 0.0f;
        const float wxb = vx1 ? wx          : 0.0f;
        const float wya = vy0 ? (1.0f - wy) : 0.0f;
        const float wyb = vy1 ? wy          : 0.0f;

        const float top = wxa * v00 + wxb * v01;
        const float bot = wxa * v10 + wxb * v11;
        acc += wya * top + wyb * bot;
    }

    acc *= (ray.w - ray.y) * (1.0f / 256.0f);

    acc += __shfl_down(acc, 32);
    acc += __shfl_down(acc, 16);
    acc += __shfl_down(acc, 8);

    if (cq == 0)
        out[(b * NANG + a) * RES + r] = acc;
}

extern "C" void kernel_launch(void* const* d_in, const int* in_sizes, int n_in,
                              void* d_out, int out_size, void* d_ws, size_t ws_size,
                              hipStream_t stream)
{
    const float* imgs   = (const float*)d_in[0];
    const float* angles = (const float*)d_in[1];
    const float* rays   = (const float*)d_in[2];
    float* out = (float*)d_out;

    if (ws_size >= PACK_BYTES) {
        f2_t* P = (f2_t*)d_ws;
        pack_dualrow<<<dim3(NB * RES), dim3(RES), 0, stream>>>(imgs, P);
        radon_fwd_packed<<<dim3(NB * NANG * 8), dim3(256), 0, stream>>>(P, angles, rays, out);
    } else {
        radon_fwd_fallback<<<dim3(NB * NANG * 8), dim3(256), 0, stream>>>(imgs, angles, rays, out);
    }
}

// Round 5
// 50.130 us; speedup vs baseline: 4.5399x; 1.0331x over previous
//
#include <hip/hip_runtime.h>

constexpr int RES  = 256;   // image resolution, rays per angle, steps per ray
constexpr int NANG = 180;
constexpr int NB   = 4;
constexpr int ROWS = RES + 1;   // padded rows: ys in [0,256]  (y = ys-1)
constexpr int COLS = RES + 2;   // padded cols: xs in [0,257]  (x = xs-1)
constexpr int SXP  = 258;       // packed row stride in float2 elements
constexpr size_t PACK_BYTES = (size_t)NB * ROWS * SXP * 8;

typedef float f2_t __attribute__((ext_vector_type(2), aligned(4)));
typedef float f4_t __attribute__((ext_vector_type(4), aligned(8)));

// ---------------------------------------------------------------------------
// Guard-band dual-row pack:
//   P[b][ys][xs] = ( img[ys-1][xs-1] or 0 , img[ys][xs-1] or 0 )
// One dwordx4 load at (ys,xs) = (y0+1, x0+1) yields (v00, v10, v01, v11)
// with out-of-image taps already EXACTLY zero -> no clamps/masks in main loop.
// All cells (including guards) are rewritten every call (d_ws is poisoned).
// ---------------------------------------------------------------------------
__global__ __launch_bounds__(256)
void pack_guard(const float* __restrict__ imgs, f2_t* __restrict__ P)
{
    const int ys = blockIdx.x % ROWS;
    const int b  = blockIdx.x / ROWS;
    const int y  = ys - 1;
    const float* __restrict__ img = imgs + b * (RES * RES);
    f2_t* __restrict__ row = P + ((size_t)b * ROWS + ys) * SXP;

    for (int xs = threadIdx.x; xs < COLS; xs += 256) {
        const int x = xs - 1;
        const bool xin = (unsigned)x < (unsigned)RES;
        f2_t v;
        v.x = ((unsigned)y       < (unsigned)RES && xin) ? img[y * RES + x]       : 0.0f;
        v.y = ((unsigned)(y + 1) < (unsigned)RES && xin) ? img[(y + 1) * RES + x] : 0.0f;
        row[xs] = v;
    }
}

// ---------------------------------------------------------------------------
// Main: lane = cq*8 + rq (8 rays x 8 step-phases -> compact ~8x8 px tile per
// wave-gather at any angle). One dwordx4 gather per sample; ~17 VALU/sample:
// 2 fma, 2 floor, 2 cvt, 2 sub, mad+shl addr, 7-op lerp. No boundary logic.
// ---------------------------------------------------------------------------
__global__ __launch_bounds__(256)
void radon_fwd_packed(const f2_t* __restrict__ P,
                      const float* __restrict__ angles,
                      const float* __restrict__ rays,
                      float* __restrict__ out)
{
    const int tid  = threadIdx.x;
    const int wave = tid >> 6;
    const int lane = tid & 63;
    const int cq   = lane >> 3;   // step phase 0..7
    const int rq   = lane & 7;    // ray within the wave's 8-ray group

    const int pair = blockIdx.x >> 3;
    const int rblk = blockIdx.x & 7;
    const int a = pair % NANG;
    const int b = pair / NANG;
    const int r = rblk * 32 + wave * 8 + rq;

    const float4 ray = reinterpret_cast<const float4*>(rays)[r];
    float sn, cs;
    sincosf(angles[a], &sn, &cs);

    const float rsx = ray.x * cs - ray.y * sn;
    const float rsy = ray.x * sn + ray.y * cs;
    const float rex = ray.z * cs - ray.w * sn;
    const float rey = ray.z * sn + ray.w * cs;

    const float ddx = rex - rsx;
    const float ddy = rey - rsy;

    // +127.5 (center) +1.0 (guard shift) + this thread's phase offset.
    // gx = fx + 1 in [0.5, 256.5]  ->  floor == trunc >= 0, index = x0+1.
    const float tb  = ((float)cq + 0.5f) * (1.0f / 256.0f);
    const float gxb = fmaf(ddx, tb, rsx + 128.5f);
    const float gyb = fmaf(ddy, tb, rsy + 128.5f);

    const f2_t* __restrict__ Pb = P + (size_t)b * ROWS * SXP;

    float acc = 0.0f;
#pragma unroll
    for (int jo = 0; jo < 32; jo += 4) {
        f4_t  p[4];
        float wx[4], wy[4];

        // --- phase 1: addresses, issue 4 independent gathers ---
#pragma unroll
        for (int u = 0; u < 4; ++u) {
            const float jf = (float)(jo + u) * (1.0f / 32.0f);
            const float gx = fmaf(ddx, jf, gxb);
            const float gy = fmaf(ddy, jf, gyb);
            const float xf = floorf(gx);
            const float yf = floorf(gy);
            wx[u] = gx - xf;
            wy[u] = gy - yf;
            const int xs = (int)xf;
            const int ys = (int)yf;
            const int off = ys * SXP + xs;
            p[u] = *reinterpret_cast<const f4_t*>(Pb + off);
        }

        // --- phase 2: consume (lerp form, taps pre-zeroed by guard band) ---
#pragma unroll
        for (int u = 0; u < 4; ++u) {
            const f4_t f4 = p[u];
            // f4 = (v00, v10, v01, v11)
            const float top = fmaf(wx[u], f4.z - f4.x, f4.x);
            const float bot = fmaf(wx[u], f4.w - f4.y, f4.y);
            acc += fmaf(wy[u], bot - top, top);
        }
    }

    acc *= (ray.w - ray.y) * (1.0f / 256.0f);   // * step

    acc += __shfl_down(acc, 32);
    acc += __shfl_down(acc, 16);
    acc += __shfl_down(acc, 8);

    if (cq == 0)
        out[(b * NANG + a) * RES + r] = acc;
}

// ---------------------------------------------------------------------------
// Fallback (no workspace): R3-style, reads imgs directly.
// ---------------------------------------------------------------------------
__global__ __launch_bounds__(256)
void radon_fwd_fallback(const float* __restrict__ imgs,
                        const float* __restrict__ angles,
                        const float* __restrict__ rays,
                        float* __restrict__ out)
{
    const int tid  = threadIdx.x;
    const int wave = tid >> 6;
    const int lane = tid & 63;
    const int cq   = lane >> 3;
    const int rq   = lane & 7;

    const int pair = blockIdx.x >> 3;
    const int rblk = blockIdx.x & 7;
    const int a = pair % NANG;
    const int b = pair / NANG;
    const int r = rblk * 32 + wave * 8 + rq;

    const float4 ray = reinterpret_cast<const float4*>(rays)[r];
    float sn, cs;
    sincosf(angles[a], &sn, &cs);

    const float rsx = ray.x * cs - ray.y * sn;
    const float rsy = ray.x * sn + ray.y * cs;
    const float rex = ray.z * cs - ray.w * sn;
    const float rey = ray.z * sn + ray.w * cs;

    const float ddx = rex - rsx;
    const float ddy = rey - rsy;
    const float bx  = rsx + 127.5f;
    const float by  = rsy + 127.5f;

    const float* __restrict__ img = imgs + b * (RES * RES);

    float acc = 0.0f;
#pragma unroll 4
    for (int j = 0; j < 32; ++j) {
        const int   i  = j * 8 + cq;
        const float t  = ((float)i + 0.5f) * (1.0f / 256.0f);
        const float fx = fmaf(ddx, t, bx);
        const float fy = fmaf(ddy, t, by);

        const float x0f = floorf(fx);
        const float y0f = floorf(fy);
        const int   x0  = (int)x0f;
        const int   y0  = (int)y0f;
        const float wxv = fx - x0f;
        const float wyv = fy - y0f;

        const int xs  = min(max(x0, 0), RES - 2);
        const int yc0 = min(max(y0, 0), RES - 1);
        const int yc1 = min(max(y0 + 1, 0), RES - 1);

        const f2_t p0 = *reinterpret_cast<const f2_t*>(img + yc0 * RES + xs);
        const f2_t p1 = *reinterpret_cast<const f2_t*>(img + yc1 * RES + xs);

        const bool straight = (x0 == xs);
        const float v00 = straight ? p0.x : p0.y;
        const float v01 = straight ? p0.y : p0.x;
        const float v10 = straight ? p1.x : p1.y;
        const float v11 = straight ? p1.y : p1.x;

        const bool vx0 = (unsigned)x0       < (unsigned)RES;
        const bool vx1 = (unsigned)(x0 + 1) < (unsigned)RES;
        const bool vy0 = (unsigned)y0       < (unsigned)RES;
        const bool vy1 = (unsigned)(y0 + 1) < (unsigned)RES;
        const float wxa = vx0 ? (1.0f - wxv) : 0.0f;
        const float wxb = vx1 ? wxv          : 0.0f;
        const float wya = vy0 ? (1.0f - wyv) : 0.0f;
        const float wyb = vy1 ? wyv          : 0.0f;

        const float top = wxa * v00 + wxb * v01;
        const float bot = wxa * v10 + wxb * v11;
        acc += wya * top + wyb * bot;
    }

    acc *= (ray.w - ray.y) * (1.0f / 256.0f);

    acc += __shfl_down(acc, 32);
    acc += __shfl_down(acc, 16);
    acc += __shfl_down(acc, 8);

    if (cq == 0)
        out[(b * NANG + a) * RES + r] = acc;
}

extern "C" void kernel_launch(void* const* d_in, const int* in_sizes, int n_in,
                              void* d_out, int out_size, void* d_ws, size_t ws_size,
                              hipStream_t stream)
{
    const float* imgs   = (const float*)d_in[0];
    const float* angles = (const float*)d_in[1];
    const float* rays   = (const float*)d_in[2];
    float* out = (float*)d_out;

    if (ws_size >= PACK_BYTES) {
        f2_t* P = (f2_t*)d_ws;
        pack_guard<<<dim3(NB * ROWS), dim3(256), 0, stream>>>(imgs, P);
        radon_fwd_packed<<<dim3(NB * NANG * 8), dim3(256), 0, stream>>>(P, angles, rays, out);
    } else {
        radon_fwd_fallback<<<dim3(NB * NANG * 8), dim3(256), 0, stream>>>(imgs, angles, rays, out);
    }
}